// Round 1
// baseline (1099.207 us; speedup 1.0000x reference)
//
#include <hip/hip_runtime.h>

#define CRF_B 512
#define CRF_T 2048
#define CRF_K 32
#define CRF_Q (CRF_T / 4)   // 512 packed-bp dwords per batch per column

// Bias making all tournament keys positive doubles. |state+trans| is bounded
// well below 2^13 (max-plus drift ~1.3/step * 2048 + slack), so d in (2^13.4, 2^14.4):
// key ulp <= 2^-38, index tag (5 bits) perturbs by < 2^-33 — far below any f32 ulp
// that can affect a comparison or the recovered value.
#define CRF_BIAS 16384.0

// One max-tree level on index-tagged f64 keys: pure v_max_f64, no VCC traffic.
// Tag = (31 - i) in low mantissa bits => equal values resolve to smaller i (first-index argmax).
template<int N>
__device__ __forceinline__ void dlevel(double (&dk)[CRF_K]) {
#pragma unroll
    for (int k = 0; k < N; ++k) dk[k] = fmax(dk[k], dk[k + N]);
}

__global__ __launch_bounds__(64, 1) void crf_fused(
    const float* __restrict__ pot,    // [B,T,K]
    const float* __restrict__ trans,  // [K,K]
    float* __restrict__ out,          // [B,T,K] one-hot fp32
    unsigned int* __restrict__ bp)    // ws: [B, Q, K] packed backpointers
{
    const int b = blockIdx.x;
    const int l = threadIdx.x;
    const int j = l & 31;             // upper half duplicates lower (benign)

    // lane j's column of transitions: tr[i] = trans[i][j]
    float tr[CRF_K];
#pragma unroll
    for (int i = 0; i < CRF_K; ++i) tr[i] = trans[i * CRF_K + j];

    const float* potb = pot + (size_t)b * (CRF_T * CRF_K);
    unsigned int* bpb = bp + (size_t)b * (CRF_Q * CRF_K);
    float* outb = out + (size_t)b * (CRF_T * CRF_K);

    float vstate = potb[j];           // t = 0
    // wave-uniform state copies (SGPRs via readlane — no DS on the hot path)
    float s[CRF_K];
#pragma unroll
    for (int i = 0; i < CRF_K; ++i)
        s[i] = __int_as_float(__builtin_amdgcn_readlane(__float_as_int(vstate), i));

    // potential double-buffer: cur = this group's pot rows, nxt = next group's
    float cur[4], nxt[4];
#pragma unroll
    for (int t = 1; t < 4; ++t) cur[t] = potb[t * CRF_K + j];

    for (int q = 0; q < CRF_Q; ++q) {
        // prefetch next group's potentials (~1 q-iter lead; clamped re-load at end)
        {
            const int tb = (q + 1) * 4;
#pragma unroll
            for (int sx = 0; sx < 4; ++sx) {
                int t = tb + sx; if (t > CRF_T - 1) t = CRF_T - 1;
                nxt[sx] = potb[t * CRF_K + j];
            }
        }
        unsigned int bpack = 0;
#pragma unroll
        for (int sx = 0; sx < 4; ++sx) {
            if (q == 0 && sx == 0) continue;   // t=0 has no backpointer
            // Build index-tagged keys: f32 add (matches reference rounding), then
            // exact f64 bias + tag OR (1 v_or_b32 on the low dword).
            double dk[CRF_K];
#pragma unroll
            for (int i = 0; i < CRF_K; ++i) {
                float v = s[i] + tr[i];
                unsigned long long u =
                    __double_as_longlong((double)v + CRF_BIAS)
                    | (unsigned long long)(31 - i);
                dk[i] = __longlong_as_double(u);
            }
            // 5-level max tree: 31 x v_max_f64, zero cmp/cndmask on the hot path.
            dlevel<16>(dk);
            dlevel<8>(dk);
            dlevel<4>(dk);
            dlevel<2>(dk);
            dlevel<1>(dk);

            unsigned long long ub = __double_as_longlong(dk[0]);
            int idx = (((int)ub) & 31) ^ 31;              // tag -> argmax index
            double dclean = __longlong_as_double(ub & ~31ull);
            vstate = (float)(dclean - CRF_BIAS) + cur[sx]; // bit-exact winner + pot
            bpack |= ((unsigned int)idx) << (8 * sx);
#pragma unroll
            for (int i = 0; i < CRF_K; ++i)
                s[i] = __int_as_float(__builtin_amdgcn_readlane(__float_as_int(vstate), i));
        }
        bpb[q * CRF_K + j] = bpack;   // halves store identical values (benign dup)
#pragma unroll
        for (int sx = 0; sx < 4; ++sx) cur[sx] = nxt[sx];
    }

    // ---------------- last tag (argmax over final state, first-index ties) ----------------
    __shared__ float fs[CRF_K];
    if (l < CRF_K) fs[l] = vstate;    // lanes 0-31 hold state[j] at lane j
    __syncthreads();
    int bt = 0; float bv = fs[0];
#pragma unroll
    for (int jj = 1; jj < CRF_K; ++jj) {
        float v = fs[jj];
        if (v > bv) { bv = v; bt = jj; }
    }
    int stag = __builtin_amdgcn_readfirstlane(bt);

    const int c = l & 31;
    // one-hot row for t = T-1 (halves write identical 128B row)
    outb[(CRF_T - 1) * CRF_K + c] = (c == stag) ? 1.0f : 0.0f;

    __threadfence();   // make own bp stores visible before read-back

    // ---------------- backtrack: lane c holds COLUMN c of bp ----------------
    for (int q0 = CRF_Q - 16; q0 >= 0; q0 -= 16) {
        unsigned int col[16];
#pragma unroll
        for (int r = 0; r < 16; ++r) col[r] = bpb[(q0 + r) * CRF_K + c];
#pragma unroll
        for (int r = 15; r >= 0; --r) {
#pragma unroll
            for (int bi = 3; bi >= 0; --bi) {
                const int t = (q0 + r) * 4 + bi;
                if (t == 0) continue;   // only q0==0, r==0, bi==0
                unsigned int dw = (unsigned int)__builtin_amdgcn_readlane((int)col[r], stag);
                stag = (int)((dw >> (8 * bi)) & 255u);
                outb[(size_t)(t - 1) * CRF_K + c] = (c == stag) ? 1.0f : 0.0f;
            }
        }
    }
}

extern "C" void kernel_launch(void* const* d_in, const int* in_sizes, int n_in,
                              void* d_out, int out_size, void* d_ws, size_t ws_size,
                              hipStream_t stream) {
    const float* pot   = (const float*)d_in[0];   // inputs [512,2048,32] fp32
    const float* trans = (const float*)d_in[1];   // transitions [32,32] fp32
    float* out = (float*)d_out;
    unsigned int* bp = (unsigned int*)d_ws;       // needs 33,554,432 B

    crf_fused<<<dim3(CRF_B), dim3(64), 0, stream>>>(pot, trans, out, bp);
}

// Round 2
// 796.674 us; speedup vs baseline: 1.3797x; 1.3797x over previous
//
#include <hip/hip_runtime.h>

#define CRF_B 512
#define CRF_T 2048
#define CRF_K 32
#define CRF_Q (CRF_T / 4)   // 512 packed-bp dwords per batch per column

// One tournament level on 16 (val, idx) pairs: reduce 2N entries to N.
// "right strictly greater" => left (lower index) wins ties => first-index argmax.
template<int N>
__device__ __forceinline__ void tlevel16(float (&val)[16], int (&idx)[16]) {
#pragma unroll
    for (int k = 0; k < N; ++k) {
        bool t = val[2 * k + 1] > val[2 * k];
        val[k] = t ? val[2 * k + 1] : val[2 * k];
        idx[k] = t ? idx[2 * k + 1] : idx[2 * k];
    }
}

__global__ __launch_bounds__(64, 1) void crf_fused(
    const float* __restrict__ pot,    // [B,T,K]
    const float* __restrict__ trans,  // [K,K]
    float* __restrict__ out,          // [B,T,K] one-hot fp32
    unsigned int* __restrict__ bp)    // ws: [B, Q, K] packed backpointers
{
    const int b = blockIdx.x;
    const int l = threadIdx.x;
    const int j = l & 31;             // output state index for this lane
    const bool hiHalf = (l >= 32);
    const int ibase = hiHalf ? 16 : 0; // this half reduces i in [ibase, ibase+16)

    // lane (j,h)'s slice of transitions: tr[m] = trans[ibase+m][j]
    float tr[16];
#pragma unroll
    for (int m = 0; m < 16; ++m) tr[m] = trans[(ibase + m) * CRF_K + j];

    // global source indices for this half's tournament (held in regs; SSA-folded)
    int iconst[16];
#pragma unroll
    for (int m = 0; m < 16; ++m) iconst[m] = ibase + m;

    const int bbase = ibase * 4;       // bpermute byte base for state fetch
    const int xaddr = (l ^ 32) * 4;    // cross-half exchange address

    const float* potb = pot + (size_t)b * (CRF_T * CRF_K);
    unsigned int* bpb = bp + (size_t)b * (CRF_Q * CRF_K);
    float* outb = out + (size_t)b * (CRF_T * CRF_K);

    float vstate = potb[j];            // t = 0 (all lanes hold state[j], halves dup)

    // potential triple-buffer: 2-q-iteration prefetch lead (~steps got faster)
    float cur[4], nxt[4], nx2[4];
    cur[0] = 0.0f;                     // never read (q==0, sx==0 skipped)
#pragma unroll
    for (int t = 1; t < 4; ++t) cur[t] = potb[t * CRF_K + j];
#pragma unroll
    for (int sx = 0; sx < 4; ++sx) nxt[sx] = potb[(4 + sx) * CRF_K + j];

    for (int q = 0; q < CRF_Q; ++q) {
        // prefetch q+2's potentials (clamped re-load at the tail)
        {
            const int tb = (q + 2) * 4;
#pragma unroll
            for (int sx = 0; sx < 4; ++sx) {
                int t = tb + sx; if (t > CRF_T - 1) t = CRF_T - 1;
                nx2[sx] = potb[t * CRF_K + j];
            }
        }
        unsigned int bpack = 0;
#pragma unroll
        for (int sx = 0; sx < 4; ++sx) {
            if (q == 0 && sx == 0) continue;   // t=0 has no backpointer
            // fetch this half's 16 source states via bpermute (LDS pipe, not VALU)
            float val[16]; int idx[16];
#pragma unroll
            for (int m = 0; m < 16; ++m) {
                float s = __int_as_float(__builtin_amdgcn_ds_bpermute(
                    bbase + 4 * m, __float_as_int(vstate)));
                val[m] = s + tr[m];
                idx[m] = iconst[m];
            }
            // 4-level tournament over 16 entries (first-index ties within half)
            tlevel16<8>(val, idx);
            tlevel16<4>(val, idx);
            tlevel16<2>(val, idx);
            tlevel16<1>(val, idx);
            // cross-half combine. Lower half covers smaller i, so on exact ties
            // the lower half's candidate must win in BOTH halves:
            //   h=0: take other iff strictly greater; h=1: take other iff >=.
            float vo = __int_as_float(__builtin_amdgcn_ds_bpermute(
                xaddr, __float_as_int(val[0])));
            int io = __builtin_amdgcn_ds_bpermute(xaddr, idx[0]);
            bool take = (vo > val[0]) || ((vo == val[0]) && hiHalf);
            float w  = take ? vo : val[0];
            int   wi = take ? io : idx[0];
            vstate = w + cur[sx];              // exact winner value + potential
            bpack |= ((unsigned int)wi) << (8 * sx);
        }
        bpb[q * CRF_K + j] = bpack;   // halves store identical values (benign dup)
#pragma unroll
        for (int sx = 0; sx < 4; ++sx) { cur[sx] = nxt[sx]; nxt[sx] = nx2[sx]; }
    }

    // ---------------- last tag (argmax over final state, first-index ties) ----------------
    __shared__ float fs[CRF_K];
    if (l < CRF_K) fs[l] = vstate;    // lanes 0-31 hold state[j] at lane j
    __syncthreads();
    int bt = 0; float bv = fs[0];
#pragma unroll
    for (int jj = 1; jj < CRF_K; ++jj) {
        float v = fs[jj];
        if (v > bv) { bv = v; bt = jj; }
    }
    int stag = __builtin_amdgcn_readfirstlane(bt);

    const int c = l & 31;
    // one-hot row for t = T-1 (halves write identical 128B row)
    outb[(CRF_T - 1) * CRF_K + c] = (c == stag) ? 1.0f : 0.0f;

    __threadfence();   // make own bp stores visible before read-back

    // ---------------- backtrack: lane c holds COLUMN c of bp ----------------
    for (int q0 = CRF_Q - 16; q0 >= 0; q0 -= 16) {
        unsigned int col[16];
#pragma unroll
        for (int r = 0; r < 16; ++r) col[r] = bpb[(q0 + r) * CRF_K + c];
#pragma unroll
        for (int r = 15; r >= 0; --r) {
#pragma unroll
            for (int bi = 3; bi >= 0; --bi) {
                const int t = (q0 + r) * 4 + bi;
                if (t == 0) continue;   // only q0==0, r==0, bi==0
                unsigned int dw = (unsigned int)__builtin_amdgcn_readlane((int)col[r], stag);
                stag = (int)((dw >> (8 * bi)) & 255u);
                outb[(size_t)(t - 1) * CRF_K + c] = (c == stag) ? 1.0f : 0.0f;
            }
        }
    }
}

extern "C" void kernel_launch(void* const* d_in, const int* in_sizes, int n_in,
                              void* d_out, int out_size, void* d_ws, size_t ws_size,
                              hipStream_t stream) {
    const float* pot   = (const float*)d_in[0];   // inputs [512,2048,32] fp32
    const float* trans = (const float*)d_in[1];   // transitions [32,32] fp32
    float* out = (float*)d_out;
    unsigned int* bp = (unsigned int*)d_ws;       // needs 33,554,432 B

    crf_fused<<<dim3(CRF_B), dim3(64), 0, stream>>>(pot, trans, out, bp);
}